// Round 1
// baseline (7292.042 us; speedup 1.0000x reference)
//
#include <hip/hip_runtime.h>
#include <hip/hip_bf16.h>

#define Bdim 256
#define Tdim 256
#define Idim 256
#define Hdim 1024
#define KDIM 1280   // I + H
#define NP   4096   // 4*H, gate-interleaved: n' = 4*hu + gate

typedef __attribute__((ext_vector_type(8)))  short short8;
typedef __attribute__((ext_vector_type(16))) float f32x16;

__device__ __forceinline__ short f2bf(float f) {
  unsigned u = __builtin_bit_cast(unsigned, f);
  unsigned r = (u + 0x7FFFu + ((u >> 16) & 1u)) >> 16;   // RNE
  return (short)r;
}
__device__ __forceinline__ float bf2f(short s) {
  unsigned u = ((unsigned)(unsigned short)s) << 16;
  return __builtin_bit_cast(float, u);
}

// ---------------- setup: Wt[n'][k] = bf16(W[k][(n'&3)*H + (n'>>2)]) ----------------
__global__ void setup_wt_kernel(const float* __restrict__ Wx,
                                const float* __restrict__ Wh,
                                short* __restrict__ Wt) {
  __shared__ float tile[64 * 65];
  const int nb = blockIdx.x, kb = blockIdx.y;
  const int tid = threadIdx.x;
#pragma unroll
  for (int i = 0; i < 16; ++i) {
    int idx = i * 256 + tid;
    int kr = idx >> 6, nc = idx & 63;
    int kglob = kb * 64 + kr;
    int np = nb * 64 + nc;
    int col = ((np & 3) << 10) | (np >> 2);
    float v = (kglob < Idim) ? Wx[(size_t)kglob * NP + col]
                             : Wh[(size_t)(kglob - Idim) * NP + col];
    tile[kr * 65 + nc] = v;
  }
  __syncthreads();
#pragma unroll
  for (int i = 0; i < 16; ++i) {
    int idx = i * 256 + tid;
    int nr = idx >> 6, kc = idx & 63;
    Wt[(size_t)(nb * 64 + nr) * KDIM + kb * 64 + kc] = f2bf(tile[kc * 65 + nr]);
  }
}

// ---------------- setup: state init + bias reorder ----------------
__global__ void setup_state_kernel(const float* __restrict__ h0,
                                   const float* __restrict__ c0,
                                   const float* __restrict__ b,
                                   short* __restrict__ Uh0,
                                   float* __restrict__ c_state,
                                   float* __restrict__ bp) {
  int idx = blockIdx.x * 256 + threadIdx.x;
  if (blockIdx.x < 1024) {          // B*H = 262144 state elems
    Uh0[idx] = f2bf(h0[idx]);
    c_state[idx] = c0[idx];
  } else {                          // 4096 bias elems
    int j = idx - 1024 * 256;
    bp[j] = b[((j & 3) << 10) | (j >> 2)];
  }
}

// ---------------- per-step fused GEMM + LSTM cell ----------------
// grid: (nt=64, mt=4), block 256 (4 waves; each wave one 32x32 quadrant of 64x64 tile)
__global__ __launch_bounds__(256) void lstm_step_kernel(
    const float* __restrict__ xin,    // (B,T,I) fp32
    const short* __restrict__ Wt,     // (NP, KDIM) bf16
    const float* __restrict__ bp,     // (NP) fp32 reordered
    const short* __restrict__ UhR,    // (B,H) bf16 h state (read)
    short* __restrict__ UhW,          // (B,H) bf16 h state (write)
    float* __restrict__ out,          // outputs base (B,T,H)
    float* __restrict__ c_state,      // (B,H) fp32 (aliases cN output)
    float* __restrict__ hN,           // (B,H) fp32 final-h output
    int t, int is_last) {
  __shared__ __align__(16) char smem[16384];
  short* As = (short*)smem;             // 64 rows x 64 k bf16, XOR-swizzled
  short* Bs = (short*)(smem + 8192);    // 64 n  x 64 k bf16, XOR-swizzled
  float* Gs = (float*)smem;             // 64 x 64 fp32 gates (reuse after K loop)

  const int tid = threadIdx.x;
  const int lane = tid & 63;
  const int wave = tid >> 6;
  const int wm = (wave >> 1) * 32, wn = (wave & 1) * 32;
  const int nt = blockIdx.x, mt = blockIdx.y;
  const int bm0 = mt * 64, n0 = nt * 64;

  f32x16 acc;
#pragma unroll
  for (int i = 0; i < 16; ++i) acc[i] = 0.0f;

  const int arow = wm + (lane & 31);
  const int brow = wn + (lane & 31);
  const int half = lane >> 5;

  for (int k0 = 0; k0 < KDIM; k0 += 64) {
    __syncthreads();
    // stage A (U_t = [x_t | h_mod]) : 512 segments of 8 bf16
#pragma unroll
    for (int s = tid; s < 512; s += 256) {
      int row = s >> 3, kseg = s & 7;
      int kg = k0 + kseg * 8;
      short8 v;
      if (kg < Idim) {
        const float* src = xin + (size_t)(bm0 + row) * (Tdim * Idim) + t * Idim + kg;
        float4 lo = *(const float4*)src;
        float4 hi = *(const float4*)(src + 4);
        v[0] = f2bf(lo.x); v[1] = f2bf(lo.y); v[2] = f2bf(lo.z); v[3] = f2bf(lo.w);
        v[4] = f2bf(hi.x); v[5] = f2bf(hi.y); v[6] = f2bf(hi.z); v[7] = f2bf(hi.w);
      } else {
        v = *(const short8*)(UhR + (size_t)(bm0 + row) * Hdim + (kg - Idim));
        if (t > 0 && kg == Idim) {
          // x_next = x + TAU * (x @ A), A = [[1.5,-1.5],[1/1.5,0]] -> cols 0,1 only
          float x0 = bf2f(v[0]), x1 = bf2f(v[1]);
          v[0] = f2bf(x0 + 0.05f * (1.5f * x0 + (1.0f / 1.5f) * x1));
          v[1] = f2bf(x1 - 0.05f * 1.5f * x0);
        }
      }
      *(short8*)(As + row * 64 + (((kseg ^ (row & 7)) & 7) << 3)) = v;
    }
    // stage B (Wt rows = output cols n')
#pragma unroll
    for (int s = tid; s < 512; s += 256) {
      int row = s >> 3, kseg = s & 7;
      short8 v = *(const short8*)(Wt + (size_t)(n0 + row) * KDIM + k0 + kseg * 8);
      *(short8*)(Bs + row * 64 + (((kseg ^ (row & 7)) & 7) << 3)) = v;
    }
    __syncthreads();
#pragma unroll
    for (int c = 0; c < 4; ++c) {
      int kseg = 2 * c + half;
      short8 af = *(const short8*)(As + arow * 64 + (((kseg ^ (arow & 7)) & 7) << 3));
      short8 bf = *(const short8*)(Bs + brow * 64 + (((kseg ^ (brow & 7)) & 7) << 3));
      acc = __builtin_amdgcn_mfma_f32_32x32x16_bf16(af, bf, acc, 0, 0, 0);
    }
  }

  // epilogue: acc (C layout col=lane&31, row=(reg&3)+8*(reg>>2)+4*(lane>>5)) -> LDS
  __syncthreads();
#pragma unroll
  for (int r = 0; r < 16; ++r) {
    int grow = wm + (r & 3) + 8 * (r >> 2) + 4 * half;
    int gcol = wn + (lane & 31);
    Gs[grow * 64 + gcol] = acc[r];
  }
  __syncthreads();

  const int u = tid & 15, r0 = tid >> 4;
  const float4 bb = ((const float4*)bp)[nt * 16 + u];
  const int hu = nt * 16 + u;
#pragma unroll
  for (int rr = r0; rr < 64; rr += 16) {
    float4 gv = *(float4*)(Gs + rr * 64 + u * 4);
    float iv = 1.0f / (1.0f + __expf(-(gv.x + bb.x)));
    float fv = 1.0f / (1.0f + __expf(-(gv.y + bb.y)));
    float gg = 2.0f / (1.0f + __expf(-2.0f * (gv.z + bb.z))) - 1.0f;  // tanh
    float ov = 1.0f / (1.0f + __expf(-(gv.w + bb.w)));
    int bm = bm0 + rr;
    size_t cidx = (size_t)bm * Hdim + hu;
    float cn = fv * c_state[cidx] + iv * gg;
    c_state[cidx] = cn;
    float hv = ov * (2.0f / (1.0f + __expf(-2.0f * cn)) - 1.0f);
    out[(size_t)bm * (Tdim * Hdim) + (size_t)t * Hdim + hu] = hv;
    UhW[cidx] = f2bf(hv);
    if (is_last) hN[cidx] = hv;
  }
}

extern "C" void kernel_launch(void* const* d_in, const int* in_sizes, int n_in,
                              void* d_out, int out_size, void* d_ws, size_t ws_size,
                              hipStream_t stream) {
  const float* xin = (const float*)d_in[0];
  const float* h0  = (const float*)d_in[1];
  const float* c0  = (const float*)d_in[2];
  const float* Wx  = (const float*)d_in[3];
  const float* Wh  = (const float*)d_in[4];
  const float* b   = (const float*)d_in[5];
  float* out = (float*)d_out;

  // workspace layout (≈11.6 MB): Wt | Uh0 | Uh1 | bp
  char* ws = (char*)d_ws;
  short* Wt  = (short*)ws;                                   // 4096*1280*2 = 10485760
  short* Uh0 = (short*)(ws + 10485760);                      // 524288
  short* Uh1 = (short*)(ws + 10485760 + 524288);             // 524288
  float* bp  = (float*)(ws + 10485760 + 1048576);            // 16384

  float* hN      = out + (size_t)Bdim * Tdim * Hdim;
  float* c_state = hN + (size_t)Bdim * Hdim;   // cN region doubles as running c

  setup_wt_kernel<<<dim3(64, 20), 256, 0, stream>>>(Wx, Wh, Wt);
  setup_state_kernel<<<1040, 256, 0, stream>>>(h0, c0, b, Uh0, c_state, bp);

  for (int t = 0; t < Tdim; ++t) {
    short* UhR = (t & 1) ? Uh1 : Uh0;
    short* UhW = (t & 1) ? Uh0 : Uh1;
    lstm_step_kernel<<<dim3(64, 4), 256, 0, stream>>>(
        xin, Wt, bp, UhR, UhW, out, c_state, hN, t, (t == Tdim - 1) ? 1 : 0);
  }
}

// Round 2
// 4714.925 us; speedup vs baseline: 1.5466x; 1.5466x over previous
//
#include <hip/hip_runtime.h>
#include <hip/hip_bf16.h>

#define Bdim 256
#define Tdim 256
#define Idim 256
#define Hdim 1024
#define KDIM 1280   // I + H
#define NP   4096   // 4*H, gate-interleaved: n' = 4*hu + gate

typedef __attribute__((ext_vector_type(8)))  short short8;
typedef __attribute__((ext_vector_type(16))) float f32x16;

__device__ __forceinline__ short f2bf(float f) {
  unsigned u = __builtin_bit_cast(unsigned, f);
  unsigned r = (u + 0x7FFFu + ((u >> 16) & 1u)) >> 16;   // RNE
  return (short)r;
}
__device__ __forceinline__ float bf2f(short s) {
  unsigned u = ((unsigned)(unsigned short)s) << 16;
  return __builtin_bit_cast(float, u);
}

// ---------------- setup: Wt[n'][k] = bf16(W[k][(n'&3)*H + (n'>>2)]) ----------------
__global__ void setup_wt_kernel(const float* __restrict__ Wx,
                                const float* __restrict__ Wh,
                                short* __restrict__ Wt) {
  __shared__ float tile[64 * 65];
  const int nb = blockIdx.x, kb = blockIdx.y;
  const int tid = threadIdx.x;
#pragma unroll
  for (int i = 0; i < 16; ++i) {
    int idx = i * 256 + tid;
    int kr = idx >> 6, nc = idx & 63;
    int kglob = kb * 64 + kr;
    int np = nb * 64 + nc;
    int col = ((np & 3) << 10) | (np >> 2);
    float v = (kglob < Idim) ? Wx[(size_t)kglob * NP + col]
                             : Wh[(size_t)(kglob - Idim) * NP + col];
    tile[kr * 65 + nc] = v;
  }
  __syncthreads();
#pragma unroll
  for (int i = 0; i < 16; ++i) {
    int idx = i * 256 + tid;
    int nr = idx >> 6, kc = idx & 63;
    Wt[(size_t)(nb * 64 + nr) * KDIM + kb * 64 + kc] = f2bf(tile[kc * 65 + nr]);
  }
}

// ---------------- setup: state init + bias reorder ----------------
__global__ void setup_state_kernel(const float* __restrict__ h0,
                                   const float* __restrict__ c0,
                                   const float* __restrict__ b,
                                   short* __restrict__ Uh0,
                                   float* __restrict__ c_state,
                                   float* __restrict__ bp) {
  int idx = blockIdx.x * 256 + threadIdx.x;
  if (blockIdx.x < 1024) {          // B*H = 262144 state elems
    Uh0[idx] = f2bf(h0[idx]);
    c_state[idx] = c0[idx];
  } else {                          // 4096 bias elems
    int j = idx - 1024 * 256;
    bp[j] = b[((j & 3) << 10) | (j >> 2)];
  }
}

// ---------------- per-step fused GEMM + LSTM cell ----------------
// grid (nt=64, mt=4), 256 threads = 4 waves. Waves split K (wave w owns
// chunks w, w+4, ..., w+16 of 20 x 64-K chunks). No LDS / no barriers in the
// K loop: MFMA fragments are loaded straight from global (lane layout of
// mfma_32x32x16 A/B frags = row (lane&31), 16B at k + (lane>>5)*8).
// One LDS round-trip at the end reduces the 4 per-wave partials and feeds
// the fused LSTM epilogue.
__global__ __launch_bounds__(256, 1) void lstm_step_kernel(
    const float* __restrict__ xin,    // (B,T,I) fp32
    const short* __restrict__ Wt,     // (NP, KDIM) bf16
    const float* __restrict__ bp,     // (NP) fp32 reordered
    const short* __restrict__ UhR,    // (B,H) bf16 h state (read)
    short* __restrict__ UhW,          // (B,H) bf16 h state (write)
    float* __restrict__ out,          // outputs base (B,T,H)
    float* __restrict__ c_state,      // (B,H) fp32 (aliases cN output)
    float* __restrict__ hN,           // (B,H) fp32 final-h output
    int t, int is_last) {
  __shared__ float Gs[4][4096];       // 64 KB: per-wave 64x64 fp32 partials

  const int tid  = threadIdx.x;
  const int lane = tid & 63;
  const int wave = tid >> 6;
  const int lrow = lane & 31;
  const int half = lane >> 5;
  const int koff = half * 8;
  const int nt = blockIdx.x, mt = blockIdx.y;
  const int bm0 = mt * 64, n0 = nt * 64;

  f32x16 acc00, acc01, acc10, acc11;
#pragma unroll
  for (int i = 0; i < 16; ++i) { acc00[i] = 0.f; acc01[i] = 0.f; acc10[i] = 0.f; acc11[i] = 0.f; }

  // per-lane fragment row bases
  const float* xr0 = xin + (size_t)(bm0 + lrow) * (Tdim * Idim) + (size_t)t * Idim;
  const float* xr1 = xr0 + (size_t)32 * (Tdim * Idim);
  const short* hr0 = UhR + (size_t)(bm0 + lrow) * Hdim;
  const short* hr1 = hr0 + 32 * Hdim;
  const short* br0 = Wt + (size_t)(n0 + lrow) * KDIM;
  const short* br1 = br0 + (size_t)32 * KDIM;

  short8 Af[2][4][2], Bf[2][4][2];    // [buf][kstep][frag]

  // chunk 0 of this wave is always an x (fp32) chunk: c = wave, kk = c*64 + ...
  {
    const int c = wave;
#pragma unroll
    for (int ks = 0; ks < 4; ++ks) {
      int kk = c * 64 + ks * 16 + koff;
      const float* p0 = xr0 + kk;
      const float* p1 = xr1 + kk;
      float4 a0 = *(const float4*)p0, a1 = *(const float4*)(p0 + 4);
      float4 c0v = *(const float4*)p1, c1v = *(const float4*)(p1 + 4);
      short8 v0, v1;
      v0[0] = f2bf(a0.x); v0[1] = f2bf(a0.y); v0[2] = f2bf(a0.z); v0[3] = f2bf(a0.w);
      v0[4] = f2bf(a1.x); v0[5] = f2bf(a1.y); v0[6] = f2bf(a1.z); v0[7] = f2bf(a1.w);
      v1[0] = f2bf(c0v.x); v1[1] = f2bf(c0v.y); v1[2] = f2bf(c0v.z); v1[3] = f2bf(c0v.w);
      v1[4] = f2bf(c1v.x); v1[5] = f2bf(c1v.y); v1[6] = f2bf(c1v.z); v1[7] = f2bf(c1v.w);
      Af[0][ks][0] = v0; Af[0][ks][1] = v1;
      Bf[0][ks][0] = *(const short8*)(br0 + kk);
      Bf[0][ks][1] = *(const short8*)(br1 + kk);
    }
  }

#pragma unroll
  for (int j = 0; j < 5; ++j) {
    // prefetch next chunk (h region, c >= 4) into the other buffer
    if (j < 4) {
      const int c = wave + 4 * (j + 1);
      const int nb = (j + 1) & 1;
#pragma unroll
      for (int ks = 0; ks < 4; ++ks) {
        int hk = c * 64 - Idim + ks * 16 + koff;
        short8 v0 = *(const short8*)(hr0 + hk);
        short8 v1 = *(const short8*)(hr1 + hk);
        if (t > 0 && c == 4 && ks == 0 && half == 0) {
          // oscillator state update on h cols 0,1 (transient, gate-input only)
          float x0 = bf2f(v0[0]), x1 = bf2f(v0[1]);
          v0[0] = f2bf(x0 + 0.05f * (1.5f * x0 + (1.0f / 1.5f) * x1));
          v0[1] = f2bf(x1 - 0.05f * 1.5f * x0);
          float y0 = bf2f(v1[0]), y1 = bf2f(v1[1]);
          v1[0] = f2bf(y0 + 0.05f * (1.5f * y0 + (1.0f / 1.5f) * y1));
          v1[1] = f2bf(y1 - 0.05f * 1.5f * y0);
        }
        Af[nb][ks][0] = v0; Af[nb][ks][1] = v1;
        int kk = c * 64 + ks * 16 + koff;
        Bf[nb][ks][0] = *(const short8*)(br0 + kk);
        Bf[nb][ks][1] = *(const short8*)(br1 + kk);
      }
    }
    const int cb = j & 1;
#pragma unroll
    for (int ks = 0; ks < 4; ++ks) {
      short8 a0 = Af[cb][ks][0], a1 = Af[cb][ks][1];
      short8 b0 = Bf[cb][ks][0], b1 = Bf[cb][ks][1];
      acc00 = __builtin_amdgcn_mfma_f32_32x32x16_bf16(a0, b0, acc00, 0, 0, 0);
      acc01 = __builtin_amdgcn_mfma_f32_32x32x16_bf16(a0, b1, acc01, 0, 0, 0);
      acc10 = __builtin_amdgcn_mfma_f32_32x32x16_bf16(a1, b0, acc10, 0, 0, 0);
      acc11 = __builtin_amdgcn_mfma_f32_32x32x16_bf16(a1, b1, acc11, 0, 0, 0);
    }
  }

  // ---- cross-wave K reduction + fused LSTM epilogue ----
  // C layout: col = lane&31, row = (r&3) + 8*(r>>2) + 4*half
#pragma unroll
  for (int r = 0; r < 16; ++r) {
    int rl = (r & 3) + 8 * (r >> 2) + 4 * half;
    Gs[wave][(rl)      * 64 + lrow]      = acc00[r];
    Gs[wave][(rl)      * 64 + 32 + lrow] = acc01[r];
    Gs[wave][(rl + 32) * 64 + lrow]      = acc10[r];
    Gs[wave][(rl + 32) * 64 + 32 + lrow] = acc11[r];
  }
  __syncthreads();

  const int u = tid & 15, r0 = tid >> 4;
  const float4 bb = ((const float4*)bp)[nt * 16 + u];
  const int hu = nt * 16 + u;
#pragma unroll
  for (int rr = r0; rr < 64; rr += 16) {
    float4 g0 = *(float4*)&Gs[0][rr * 64 + u * 4];
    float4 g1 = *(float4*)&Gs[1][rr * 64 + u * 4];
    float4 g2 = *(float4*)&Gs[2][rr * 64 + u * 4];
    float4 g3 = *(float4*)&Gs[3][rr * 64 + u * 4];
    float gx = g0.x + g1.x + g2.x + g3.x + bb.x;
    float gy = g0.y + g1.y + g2.y + g3.y + bb.y;
    float gz = g0.z + g1.z + g2.z + g3.z + bb.z;
    float gw = g0.w + g1.w + g2.w + g3.w + bb.w;
    float iv = 1.0f / (1.0f + __expf(-gx));
    float fv = 1.0f / (1.0f + __expf(-gy));
    float gg = 2.0f / (1.0f + __expf(-2.0f * gz)) - 1.0f;  // tanh
    float ov = 1.0f / (1.0f + __expf(-gw));
    int bm = bm0 + rr;
    size_t cidx = (size_t)bm * Hdim + hu;
    float cn = fv * c_state[cidx] + iv * gg;
    c_state[cidx] = cn;
    float hv = ov * (2.0f / (1.0f + __expf(-2.0f * cn)) - 1.0f);
    out[(size_t)bm * (Tdim * Hdim) + (size_t)t * Hdim + hu] = hv;
    UhW[cidx] = f2bf(hv);
    if (is_last) hN[cidx] = hv;
  }
}

extern "C" void kernel_launch(void* const* d_in, const int* in_sizes, int n_in,
                              void* d_out, int out_size, void* d_ws, size_t ws_size,
                              hipStream_t stream) {
  const float* xin = (const float*)d_in[0];
  const float* h0  = (const float*)d_in[1];
  const float* c0  = (const float*)d_in[2];
  const float* Wx  = (const float*)d_in[3];
  const float* Wh  = (const float*)d_in[4];
  const float* b   = (const float*)d_in[5];
  float* out = (float*)d_out;

  // workspace layout (~11.6 MB): Wt | Uh0 | Uh1 | bp
  char* ws = (char*)d_ws;
  short* Wt  = (short*)ws;                                   // 4096*1280*2 = 10485760
  short* Uh0 = (short*)(ws + 10485760);                      // 524288
  short* Uh1 = (short*)(ws + 10485760 + 524288);             // 524288
  float* bp  = (float*)(ws + 10485760 + 1048576);            // 16384

  float* hN      = out + (size_t)Bdim * Tdim * Hdim;
  float* c_state = hN + (size_t)Bdim * Hdim;   // cN region doubles as running c

  setup_wt_kernel<<<dim3(64, 20), 256, 0, stream>>>(Wx, Wh, Wt);
  setup_state_kernel<<<1040, 256, 0, stream>>>(h0, c0, b, Uh0, c_state, bp);

  for (int t = 0; t < Tdim; ++t) {
    short* UhR = (t & 1) ? Uh1 : Uh0;
    short* UhW = (t & 1) ? Uh0 : Uh1;
    lstm_step_kernel<<<dim3(64, 4), 256, 0, stream>>>(
        xin, Wt, bp, UhR, UhW, out, c_state, hN, t, (t == Tdim - 1) ? 1 : 0);
  }
}